// Round 8
// baseline (212.891 us; speedup 1.0000x reference)
//
#include <hip/hip_runtime.h>

// Problem constants (match reference)
#define N_PTS 32768
#define E_EDGES 524288
#define THREADS 256
#define RPT 8                                // rows per thread (4 packed pairs)
#define RBLOCK (THREADS * RPT)               // 2048 rows per supertile
#define CCHUNK 16                            // j columns per block (fine quantum: NB/slots = 8.5 -> 94% util)
#define NB 17408                             // sum_{I=0..15} (2048 - 128*I)
#define EPB 31                               // attract edges per block (31*17408 >= E)
#define NSLOTS 64                            // spread accumulator slots

typedef float f32x2 __attribute__((ext_vector_type(2)));

// Packed f32 VOP3P ops (issue compression: 2 rows per instruction)
#define PK_SUB(d, a, b) \
    asm("v_pk_add_f32 %0, %1, %2 neg_lo:[0,1] neg_hi:[0,1]" : "=v"(d) : "v"(a), "v"(b))
#define PK_FMA(d, a, b, c) \
    asm("v_pk_fma_f32 %0, %1, %2, %3" : "=v"(d) : "v"(a), "v"(b), "v"(c))
#define PK_MUL_IP(d, a) \
    asm("v_pk_mul_f32 %0, %0, %1" : "+v"(d) : "v"(a))

// ws layout: ws[0..63] = acc_r slots, ws[64..127] = acc_a slots (doubles)

__global__ __launch_bounds__(128) void init_acc_kernel(double* ws) {
    ws[threadIdx.x] = 0.0;
}

// Fused kernel: repulsive triangle-dual tile + a 31-edge attract prologue.
//
// Repulsive (L_ij = L_ji): 16 supertiles of 2048 rows; strict-upper j-chunks
// (16 cols) use dual row+col accumulation covering (i,j) and (j,i); diagonal
// supertiles computed full, row-side only.
// Per pair: b = 1+dx^2+dy^2 (>=1 in fp, no clamp); a = fma(b,1+eps,-1).
// Row chains: per-row product over 8-j group -> 2 logs, weight d_i.
// Col chains: product over thread's 8 rows per j -> 2 logs, weight d_j.
__global__ __launch_bounds__(256) void fused_kernel(
    const float* __restrict__ emb,
    const float* __restrict__ deg,
    const float* __restrict__ sparse,
    const int* __restrict__ heads,
    const int* __restrict__ tails,
    double* __restrict__ acc) {
    // ---- attract prologue: one edge per thread (t < EPB) ----
    float aLocal = 0.0f;
    {
        int e = blockIdx.x * EPB + threadIdx.x;
        if (threadIdx.x < EPB && e < E_EDGES) {
            int h = heads[e], t = tails[e];
            float2 eh = *reinterpret_cast<const float2*>(emb + 2 * h);
            float2 et = *reinterpret_cast<const float2*>(emb + 2 * t);
            float dx = eh.x - et.x;
            float dy = eh.y - et.y;
            float sqd = fmaf(dx, dx, dy * dy);
            aLocal = sparse[e] * __log2f(1.0f + sqd);
        }
    }

    // ---- map blockIdx -> (supertile I, chunk w); block-uniform, <=16 iters ----
    int w = blockIdx.x, I = 0, cnt = 2048;
    while (w >= cnt) { w -= cnt; ++I; cnt -= 128; }
    const int JG = (I << 7) + w;     // global 16-col chunk index
    const bool diag = (w < 128);     // chunk inside the diagonal supertile

    const int ibase = (I << 11) + threadIdx.x;

    f32x2 rx[4], ry[4];
    #pragma unroll
    for (int p = 0; p < 4; ++p) {
        float2 pA = *reinterpret_cast<const float2*>(emb + 2 * (ibase + (2 * p + 0) * THREADS));
        float2 pB = *reinterpret_cast<const float2*>(emb + 2 * (ibase + (2 * p + 1) * THREADS));
        rx[p] = (f32x2){pA.x, pB.x};
        ry[p] = (f32x2){pA.y, pB.y};
    }

    const f32x2 ONE2 = {1.0f, 1.0f};
    const f32x2 EPS2 = {1.0001f, 1.0001f};
    const f32x2 M1_2 = {-1.0f, -1.0f};

    float S[8];
    #pragma unroll
    for (int r = 0; r < 8; ++r) S[r] = 0.0f;
    float colAcc = 0.0f;

    const float4* __restrict__ P4 = reinterpret_cast<const float4*>(emb) + (JG << 3);
    const float* __restrict__ djp = deg + (JG << 4);

#define CORE(p, FJ, CM)                                           \
    {                                                             \
        f32x2 dx_, dy_, t_, b_, a_;                               \
        PK_SUB(dx_, rx[p], Jx);                                   \
        PK_SUB(dy_, ry[p], Jy);                                   \
        PK_FMA(t_, dy_, dy_, ONE2);                               \
        PK_FMA(b_, dx_, dx_, t_);                                 \
        PK_FMA(a_, b_, EPS2, M1_2);                               \
        if (FJ) { pa[p] = a_; pb[p] = b_; }                       \
        else    { PK_MUL_IP(pa[p], a_); PK_MUL_IP(pb[p], b_); }   \
        if (CM == 1) { pc_a = a_; pc_b = b_; }                    \
        if (CM == 2) { PK_MUL_IP(pc_a, a_); PK_MUL_IP(pc_b, b_); }\
    }

#define OFFJ(FJ, xj, yj, dval)                                    \
    {                                                             \
        f32x2 Jx = {(xj), (xj)}, Jy = {(yj), (yj)};               \
        f32x2 pc_a, pc_b;                                         \
        CORE(0, FJ, 1) CORE(1, FJ, 2) CORE(2, FJ, 2) CORE(3, FJ, 2) \
        float qa_ = pc_a.x * pc_a.y;                              \
        float qb_ = pc_b.x * pc_b.y;                              \
        colAcc = fmaf((dval), __log2f(qa_) - __log2f(qb_), colAcc); \
    }

#define DIAJ(FJ, xj, yj)                                          \
    {                                                             \
        f32x2 Jx = {(xj), (xj)}, Jy = {(yj), (yj)};               \
        f32x2 pc_a, pc_b; (void)pc_a; (void)pc_b;                 \
        CORE(0, FJ, 0) CORE(1, FJ, 0) CORE(2, FJ, 0) CORE(3, FJ, 0) \
    }

#define ROWFLUSH                                                  \
    _Pragma("unroll")                                             \
    for (int p = 0; p < 4; ++p) {                                 \
        S[2 * p + 0] += __log2f(pa[p].x) - __log2f(pb[p].x);      \
        S[2 * p + 1] += __log2f(pa[p].y) - __log2f(pb[p].y);      \
    }

    if (!diag) {
        #pragma unroll
        for (int g = 0; g < CCHUNK / 8; ++g) {
            float4 A = P4[4 * g + 0];
            float4 B = P4[4 * g + 1];
            float4 C = P4[4 * g + 2];
            float4 D = P4[4 * g + 3];
            float d0 = djp[8 * g + 0], d1 = djp[8 * g + 1];
            float d2 = djp[8 * g + 2], d3 = djp[8 * g + 3];
            float d4 = djp[8 * g + 4], d5 = djp[8 * g + 5];
            float d6 = djp[8 * g + 6], d7 = djp[8 * g + 7];
            f32x2 pa[4], pb[4];
            OFFJ(1, A.x, A.y, d0) OFFJ(0, A.z, A.w, d1)
            OFFJ(0, B.x, B.y, d2) OFFJ(0, B.z, B.w, d3)
            OFFJ(0, C.x, C.y, d4) OFFJ(0, C.z, C.w, d5)
            OFFJ(0, D.x, D.y, d6) OFFJ(0, D.z, D.w, d7)
            ROWFLUSH
        }
    } else {
        #pragma unroll
        for (int g = 0; g < CCHUNK / 8; ++g) {
            float4 A = P4[4 * g + 0];
            float4 B = P4[4 * g + 1];
            float4 C = P4[4 * g + 2];
            float4 D = P4[4 * g + 3];
            f32x2 pa[4], pb[4];
            DIAJ(1, A.x, A.y) DIAJ(0, A.z, A.w)
            DIAJ(0, B.x, B.y) DIAJ(0, B.z, B.w)
            DIAJ(0, C.x, C.y) DIAJ(0, C.z, C.w)
            DIAJ(0, D.x, D.y) DIAJ(0, D.z, D.w)
            ROWFLUSH
        }
    }
#undef CORE
#undef OFFJ
#undef DIAJ
#undef ROWFLUSH

    float contrib = colAcc;
    #pragma unroll
    for (int p = 0; p < 4; ++p) {
        contrib = fmaf(deg[ibase + (2 * p + 0) * THREADS], S[2 * p + 0], contrib);
        contrib = fmaf(deg[ibase + (2 * p + 1) * THREADS], S[2 * p + 1], contrib);
    }
    for (int off = 32; off; off >>= 1) {
        contrib += __shfl_down(contrib, off, 64);
        aLocal  += __shfl_down(aLocal,  off, 64);
    }
    if ((threadIdx.x & 63) == 0) {
        int slot = blockIdx.x & (NSLOTS - 1);
        atomicAdd(&acc[slot], (double)contrib);
        atomicAdd(&acc[NSLOTS + slot], (double)aLocal);
    }
}

__global__ void finalize_kernel(const double* __restrict__ acc, float* __restrict__ out) {
    const double LN2 = 0.6931471805599453;
    double acc_r = 0.0, acc_a = 0.0;
    for (int s = 0; s < NSLOTS; ++s) { acc_r += acc[s]; acc_a += acc[NSLOTS + s]; }
    double loss = LN2 * (acc_a - (10.0 / 65536.0) * acc_r);
    out[0] = (float)loss;
}

extern "C" void kernel_launch(void* const* d_in, const int* in_sizes, int n_in,
                              void* d_out, int out_size, void* d_ws, size_t ws_size,
                              hipStream_t stream) {
    const float* emb    = (const float*)d_in[0];
    const float* sparse = (const float*)d_in[1];
    const float* deg    = (const float*)d_in[2];
    const int*   heads  = (const int*)d_in[3];
    const int*   tails  = (const int*)d_in[4];
    float* out = (float*)d_out;
    double* ws = (double*)d_ws;

    hipLaunchKernelGGL(init_acc_kernel, dim3(1), dim3(128), 0, stream, ws);
    hipLaunchKernelGGL(fused_kernel, dim3(NB), dim3(256), 0, stream,
                       emb, deg, sparse, heads, tails, ws);
    hipLaunchKernelGGL(finalize_kernel, dim3(1), dim3(1), 0, stream, ws, out);
}

// Round 10
// 126.633 us; speedup vs baseline: 1.6812x; 1.6812x over previous
//
#include <hip/hip_runtime.h>

// Problem constants (match reference)
#define N_PTS 32768
#define E_EDGES 524288
#define THREADS 256
#define RPT 8                    // rows per thread (4 packed pairs)
#define RBLOCK 2048              // rows per supertile (256 threads x 8)
#define NB 2048                  // blocks; 34816 chunks = NB x 17 exactly
#define CPB 17                   // 8-col chunks per block
#define NSLOTS 64                // spread accumulator slots

typedef float f32x2 __attribute__((ext_vector_type(2)));

// Packed f32 VOP3P ops (issue compression: 2 rows per instruction)
#define PK_SUB(d, a, b) \
    asm("v_pk_add_f32 %0, %1, %2 neg_lo:[0,1] neg_hi:[0,1]" : "=v"(d) : "v"(a), "v"(b))
#define PK_FMA(d, a, b, c) \
    asm("v_pk_fma_f32 %0, %1, %2, %3" : "=v"(d) : "v"(a), "v"(b), "v"(c))
#define PK_MUL_IP(d, a) \
    asm("v_pk_mul_f32 %0, %0, %1" : "+v"(d) : "v"(a))

// ws layout: ws[0..63] = acc_r slots, ws[64..127] = acc_a slots (doubles)

__global__ __launch_bounds__(128) void init_acc_kernel(double* ws) {
    ws[threadIdx.x] = 0.0;
}

// chunk prefix: supertile I owns chunks [pfx(I), pfx(I+1)), pfx(I) = 4096*I - 128*I*(I-1)
__device__ __forceinline__ int pfx(int I) { return 4096 * I - 128 * I * (I - 1); }

// Fused kernel: 17-chunk row-strip repulsive + 256-edge attract (1 edge/thread).
// Repulsive (L_ij = L_ji): supertile I rows (2048, in regs) vs consecutive
// 8-col chunks starting at j = 2048*I. Diagonal-supertile chunks: row-side
// only. Off-diag chunks: dual row+col accumulation covers (i,j) and (j,i).
// Per pair: b = 1+dx^2+dy^2 (>=1 in fp, no clamp); a = fma(b,1+eps,-1).
__global__ __launch_bounds__(256) void fused_kernel(
    const float* __restrict__ emb,
    const float* __restrict__ deg,
    const float* __restrict__ sparse,
    const int* __restrict__ heads,
    const int* __restrict__ tails,
    double* __restrict__ acc) {
    // ---- attract: exactly one edge per thread (2048*256 == E) ----
    float aLocal;
    {
        int e = (blockIdx.x << 8) + threadIdx.x;
        int h = heads[e], t = tails[e];
        float2 eh = *reinterpret_cast<const float2*>(emb + 2 * h);
        float2 et = *reinterpret_cast<const float2*>(emb + 2 * t);
        float dx = eh.x - et.x;
        float dy = eh.y - et.y;
        float sqd = fmaf(dx, dx, dy * dy);
        aLocal = sparse[e] * __log2f(1.0f + sqd);
    }

    const f32x2 ONE2 = {1.0f, 1.0f};
    const f32x2 EPS2 = {1.0001f, 1.0001f};
    const f32x2 M1_2 = {-1.0f, -1.0f};

    const int c0 = blockIdx.x * CPB;

    // initial supertile for this strip (scalar scan, <=16 iters)
    int curI = 0;
    while (pfx(curI + 1) <= c0) ++curI;
    int nextB = pfx(curI + 1);

    // load rows of supertile curI
    f32x2 rx[4], ry[4];
    int ibase = (curI << 11) + threadIdx.x;
#define LOADROWS                                                               \
    _Pragma("unroll")                                                          \
    for (int p = 0; p < 4; ++p) {                                              \
        float2 pA = *reinterpret_cast<const float2*>(emb + 2 * (ibase + (2 * p + 0) * THREADS)); \
        float2 pB = *reinterpret_cast<const float2*>(emb + 2 * (ibase + (2 * p + 1) * THREADS)); \
        rx[p] = (f32x2){pA.x, pB.x};                                           \
        ry[p] = (f32x2){pA.y, pB.y};                                           \
    }
    LOADROWS

    float S[8];
    #pragma unroll
    for (int r = 0; r < 8; ++r) S[r] = 0.0f;
    float contrib = 0.0f;

#define FLUSHS                                                                 \
    _Pragma("unroll")                                                          \
    for (int p = 0; p < 4; ++p) {                                              \
        contrib = fmaf(deg[ibase + (2 * p + 0) * THREADS], S[2 * p + 0], contrib); \
        contrib = fmaf(deg[ibase + (2 * p + 1) * THREADS], S[2 * p + 1], contrib); \
        S[2 * p + 0] = 0.0f; S[2 * p + 1] = 0.0f;                              \
    }

#define CORE(p, FJ, CM)                                           \
    {                                                             \
        f32x2 dx_, dy_, t_, b_, a_;                               \
        PK_SUB(dx_, rx[p], Jx);                                   \
        PK_SUB(dy_, ry[p], Jy);                                   \
        PK_FMA(t_, dy_, dy_, ONE2);                               \
        PK_FMA(b_, dx_, dx_, t_);                                 \
        PK_FMA(a_, b_, EPS2, M1_2);                               \
        if (FJ) { pa[p] = a_; pb[p] = b_; }                       \
        else    { PK_MUL_IP(pa[p], a_); PK_MUL_IP(pb[p], b_); }   \
        if (CM == 1) { pc_a = a_; pc_b = b_; }                    \
        if (CM == 2) { PK_MUL_IP(pc_a, a_); PK_MUL_IP(pc_b, b_); }\
    }

#define OFFJ(FJ, xj, yj, dval)                                    \
    {                                                             \
        f32x2 Jx = {(xj), (xj)}, Jy = {(yj), (yj)};               \
        f32x2 pc_a, pc_b;                                         \
        CORE(0, FJ, 1) CORE(1, FJ, 2) CORE(2, FJ, 2) CORE(3, FJ, 2) \
        float qa_ = pc_a.x * pc_a.y;                              \
        float qb_ = pc_b.x * pc_b.y;                              \
        colAcc = fmaf((dval), __log2f(qa_) - __log2f(qb_), colAcc); \
    }

#define DIAJ(FJ, xj, yj)                                          \
    {                                                             \
        f32x2 Jx = {(xj), (xj)}, Jy = {(yj), (yj)};               \
        f32x2 pc_a, pc_b; (void)pc_a; (void)pc_b;                 \
        CORE(0, FJ, 0) CORE(1, FJ, 0) CORE(2, FJ, 0) CORE(3, FJ, 0) \
    }

#define ROWFLUSH                                                  \
    _Pragma("unroll")                                             \
    for (int p = 0; p < 4; ++p) {                                 \
        S[2 * p + 0] += __log2f(pa[p].x) - __log2f(pb[p].x);      \
        S[2 * p + 1] += __log2f(pa[p].y) - __log2f(pb[p].y);      \
    }

    float colAcc = 0.0f;

    #pragma unroll 1
    for (int k = 0; k < CPB; ++k) {
        int c = c0 + k;
        if (c >= nextB) {          // supertile boundary (<=1 per block)
            FLUSHS
            ++curI;
            nextB = pfx(curI + 1);
            ibase = (curI << 11) + threadIdx.x;
            LOADROWS
        }
        int w = c - pfx(curI);                 // chunk index within supertile
        int j0 = (curI << 11) + (w << 3);      // first j column
        const float4* __restrict__ P4b = reinterpret_cast<const float4*>(emb) + (j0 >> 1);
        float4 A = P4b[0], B = P4b[1], C = P4b[2], D = P4b[3];
        f32x2 pa[4], pb[4];

        if (w >= 256) {            // off-diagonal: dual row+col accumulation
            const float4* dj = reinterpret_cast<const float4*>(deg + j0);
            float4 dj0 = dj[0], dj1 = dj[1];
            OFFJ(1, A.x, A.y, dj0.x) OFFJ(0, A.z, A.w, dj0.y)
            OFFJ(0, B.x, B.y, dj0.z) OFFJ(0, B.z, B.w, dj0.w)
            OFFJ(0, C.x, C.y, dj1.x) OFFJ(0, C.z, C.w, dj1.y)
            OFFJ(0, D.x, D.y, dj1.z) OFFJ(0, D.z, D.w, dj1.w)
        } else {                   // diagonal supertile: row-side only
            DIAJ(1, A.x, A.y) DIAJ(0, A.z, A.w)
            DIAJ(0, B.x, B.y) DIAJ(0, B.z, B.w)
            DIAJ(0, C.x, C.y) DIAJ(0, C.z, C.w)
            DIAJ(0, D.x, D.y) DIAJ(0, D.z, D.w)
        }
        ROWFLUSH
    }
    FLUSHS
    contrib += colAcc;

#undef CORE
#undef OFFJ
#undef DIAJ
#undef ROWFLUSH
#undef FLUSHS
#undef LOADROWS

    for (int off = 32; off; off >>= 1) {
        contrib += __shfl_down(contrib, off, 64);
        aLocal  += __shfl_down(aLocal,  off, 64);
    }
    if ((threadIdx.x & 63) == 0) {
        int slot = blockIdx.x & (NSLOTS - 1);
        atomicAdd(&acc[slot], (double)contrib);
        atomicAdd(&acc[NSLOTS + slot], (double)aLocal);
    }
}

__global__ void finalize_kernel(const double* __restrict__ acc, float* __restrict__ out) {
    const double LN2 = 0.6931471805599453;
    double acc_r = 0.0, acc_a = 0.0;
    for (int s = 0; s < NSLOTS; ++s) { acc_r += acc[s]; acc_a += acc[NSLOTS + s]; }
    double loss = LN2 * (acc_a - (10.0 / 65536.0) * acc_r);
    out[0] = (float)loss;
}

extern "C" void kernel_launch(void* const* d_in, const int* in_sizes, int n_in,
                              void* d_out, int out_size, void* d_ws, size_t ws_size,
                              hipStream_t stream) {
    const float* emb    = (const float*)d_in[0];
    const float* sparse = (const float*)d_in[1];
    const float* deg    = (const float*)d_in[2];
    const int*   heads  = (const int*)d_in[3];
    const int*   tails  = (const int*)d_in[4];
    float* out = (float*)d_out;
    double* ws = (double*)d_ws;

    hipLaunchKernelGGL(init_acc_kernel, dim3(1), dim3(128), 0, stream, ws);
    hipLaunchKernelGGL(fused_kernel, dim3(NB), dim3(256), 0, stream,
                       emb, deg, sparse, heads, tails, ws);
    hipLaunchKernelGGL(finalize_kernel, dim3(1), dim3(1), 0, stream, ws, out);
}

// Round 11
// 117.713 us; speedup vs baseline: 1.8086x; 1.0758x over previous
//
#include <hip/hip_runtime.h>

// Problem constants (match reference)
#define N_PTS 32768
#define E_EDGES 524288
#define THREADS 256
#define NB_HEAVY 8192            // 32-col blocks: exactly 4.0 rounds at 2048 residency
#define NB_LIGHT 1024            // 16-col blocks (supertile 0 off-diag), half-duration tail
#define NB 9216
#define EPB 57                   // attract edges per block (57*9216 >= E)
#define NSLOTS 64                // spread accumulator slots

typedef float f32x2 __attribute__((ext_vector_type(2)));

// Packed f32 VOP3P ops
#define PK_SUB(d, a, b) \
    asm("v_pk_add_f32 %0, %1, %2 neg_lo:[0,1] neg_hi:[0,1]" : "=v"(d) : "v"(a), "v"(b))
#define PK_FMA(d, a, b, c) \
    asm("v_pk_fma_f32 %0, %1, %2, %3" : "=v"(d) : "v"(a), "v"(b), "v"(c))
#define PK_MUL_IP(d, a) \
    asm("v_pk_mul_f32 %0, %0, %1" : "+v"(d) : "v"(a))

// ws layout: ws[0..63] = acc_r slots, ws[64..127] = acc_a slots (doubles)

__global__ __launch_bounds__(128) void init_acc_kernel(double* ws) {
    ws[threadIdx.x] = 0.0;
}

// Fused kernel. Repulsive (L_ij = L_ji): supertile I = rows [2048I, 2048(I+1)).
// Each block: one supertile, one contiguous col range (32 or 16 cols), never
// crossing a supertile boundary. Diagonal region (first 2048 cols): row-side
// only, full square. Off-diag: dual row+col accumulation covers (i,j)+(j,i).
// Per pair: b = 1+dx^2+dy^2 (>=1 in fp, no clamp); a = fma(b,1+eps,-1).
__global__ __launch_bounds__(256) void fused_kernel(
    const float* __restrict__ emb,
    const float* __restrict__ deg,
    const float* __restrict__ sparse,
    const int* __restrict__ heads,
    const int* __restrict__ tails,
    double* __restrict__ acc) {
    const int b = blockIdx.x;
    const int tid = threadIdx.x;

    // ---- attract prefetch: issue index/weight loads now, compute later ----
    int eh_i = 0, et_i = 0;
    float sp = 0.0f;
    const int e = b * EPB + tid;
    const bool doE = (tid < EPB) && (e < E_EDGES);
    if (doE) { eh_i = heads[e]; et_i = tails[e]; sp = sparse[e]; }

    // ---- map blockIdx -> (supertile I, col0, ngroups, diag) ----
    int I, col0, ngroups;
    bool diag;
    if (b >= NB_HEAVY) {            // light tail: supertile 0, cols [16384,32768)
        I = 0; col0 = 16384 + ((b - NB_HEAVY) << 4); ngroups = 2; diag = false;
    } else if (b < 512) {           // supertile 0 heavy: cols [0,16384)
        I = 0; col0 = b << 5; ngroups = 4; diag = (b < 64);
    } else {                        // supertiles 1..15, 1024-64*I blocks each
        int w = b - 512; I = 1; int cnt = 960;
        while (w >= cnt) { w -= cnt; ++I; cnt -= 64; }
        col0 = (I << 11) + (w << 5); ngroups = 4; diag = (w < 64);
    }

    const f32x2 ONE2 = {1.0f, 1.0f};
    const f32x2 EPS2 = {1.0001f, 1.0001f};
    const f32x2 M1_2 = {-1.0f, -1.0f};

    // rows of supertile I (8 per thread, 4 packed pairs)
    const int ibase = (I << 11) + tid;
    f32x2 rx[4], ry[4];
    #pragma unroll
    for (int p = 0; p < 4; ++p) {
        float2 pA = *reinterpret_cast<const float2*>(emb + 2 * (ibase + (2 * p + 0) * THREADS));
        float2 pB = *reinterpret_cast<const float2*>(emb + 2 * (ibase + (2 * p + 1) * THREADS));
        rx[p] = (f32x2){pA.x, pB.x};
        ry[p] = (f32x2){pA.y, pB.y};
    }

    float S[8];
    #pragma unroll
    for (int r = 0; r < 8; ++r) S[r] = 0.0f;
    float colAcc = 0.0f;

#define CORE(p, FJ, CM)                                           \
    {                                                             \
        f32x2 dx_, dy_, t_, b_, a_;                               \
        PK_SUB(dx_, rx[p], Jx);                                   \
        PK_SUB(dy_, ry[p], Jy);                                   \
        PK_FMA(t_, dy_, dy_, ONE2);                               \
        PK_FMA(b_, dx_, dx_, t_);                                 \
        PK_FMA(a_, b_, EPS2, M1_2);                               \
        if (FJ) { pa[p] = a_; pb[p] = b_; }                       \
        else    { PK_MUL_IP(pa[p], a_); PK_MUL_IP(pb[p], b_); }   \
        if (CM == 1) { pc_a = a_; pc_b = b_; }                    \
        if (CM == 2) { PK_MUL_IP(pc_a, a_); PK_MUL_IP(pc_b, b_); }\
    }

#define OFFJ(FJ, xj, yj, dval)                                    \
    {                                                             \
        f32x2 Jx = {(xj), (xj)}, Jy = {(yj), (yj)};               \
        f32x2 pc_a, pc_b;                                         \
        CORE(0, FJ, 1) CORE(1, FJ, 2) CORE(2, FJ, 2) CORE(3, FJ, 2) \
        float qa_ = pc_a.x * pc_a.y;                              \
        float qb_ = pc_b.x * pc_b.y;                              \
        colAcc = fmaf((dval), __log2f(qa_) - __log2f(qb_), colAcc); \
    }

#define DIAJ(FJ, xj, yj)                                          \
    {                                                             \
        f32x2 Jx = {(xj), (xj)}, Jy = {(yj), (yj)};               \
        f32x2 pc_a, pc_b; (void)pc_a; (void)pc_b;                 \
        CORE(0, FJ, 0) CORE(1, FJ, 0) CORE(2, FJ, 0) CORE(3, FJ, 0) \
    }

#define ROWFLUSH                                                  \
    _Pragma("unroll")                                             \
    for (int p = 0; p < 4; ++p) {                                 \
        S[2 * p + 0] += __log2f(pa[p].x) - __log2f(pb[p].x);      \
        S[2 * p + 1] += __log2f(pa[p].y) - __log2f(pb[p].y);      \
    }

    const float4* __restrict__ P4 = reinterpret_cast<const float4*>(emb) + (col0 >> 1);
    if (!diag) {
        for (int g = 0; g < ngroups; ++g) {
            const float4* P4b = P4 + (g << 2);
            float4 A = P4b[0], B = P4b[1], C = P4b[2], D = P4b[3];
            const float4* dj = reinterpret_cast<const float4*>(deg + col0) + (g << 1);
            float4 dj0 = dj[0], dj1 = dj[1];
            f32x2 pa[4], pb[4];
            OFFJ(1, A.x, A.y, dj0.x) OFFJ(0, A.z, A.w, dj0.y)
            OFFJ(0, B.x, B.y, dj0.z) OFFJ(0, B.z, B.w, dj0.w)
            OFFJ(0, C.x, C.y, dj1.x) OFFJ(0, C.z, C.w, dj1.y)
            OFFJ(0, D.x, D.y, dj1.z) OFFJ(0, D.z, D.w, dj1.w)
            ROWFLUSH
        }
    } else {
        for (int g = 0; g < ngroups; ++g) {
            const float4* P4b = P4 + (g << 2);
            float4 A = P4b[0], B = P4b[1], C = P4b[2], D = P4b[3];
            f32x2 pa[4], pb[4];
            DIAJ(1, A.x, A.y) DIAJ(0, A.z, A.w)
            DIAJ(0, B.x, B.y) DIAJ(0, B.z, B.w)
            DIAJ(0, C.x, C.y) DIAJ(0, C.z, C.w)
            DIAJ(0, D.x, D.y) DIAJ(0, D.z, D.w)
            ROWFLUSH
        }
    }
#undef CORE
#undef OFFJ
#undef DIAJ
#undef ROWFLUSH

    // row flush: weight by d_i
    float contrib = colAcc;
    #pragma unroll
    for (int p = 0; p < 4; ++p) {
        contrib = fmaf(deg[ibase + (2 * p + 0) * THREADS], S[2 * p + 0], contrib);
        contrib = fmaf(deg[ibase + (2 * p + 1) * THREADS], S[2 * p + 1], contrib);
    }

    // ---- attract epilogue: gathers + log (indices prefetched at top) ----
    float aLocal = 0.0f;
    if (doE) {
        float2 eh = *reinterpret_cast<const float2*>(emb + 2 * eh_i);
        float2 et = *reinterpret_cast<const float2*>(emb + 2 * et_i);
        float dx = eh.x - et.x;
        float dy = eh.y - et.y;
        float sqd = fmaf(dx, dx, dy * dy);
        aLocal = sp * __log2f(1.0f + sqd);
    }

    for (int off = 32; off; off >>= 1) {
        contrib += __shfl_down(contrib, off, 64);
        aLocal  += __shfl_down(aLocal,  off, 64);
    }
    if ((tid & 63) == 0) {
        int slot = b & (NSLOTS - 1);
        atomicAdd(&acc[slot], (double)contrib);
        atomicAdd(&acc[NSLOTS + slot], (double)aLocal);
    }
}

__global__ void finalize_kernel(const double* __restrict__ acc, float* __restrict__ out) {
    const double LN2 = 0.6931471805599453;
    double acc_r = 0.0, acc_a = 0.0;
    for (int s = 0; s < NSLOTS; ++s) { acc_r += acc[s]; acc_a += acc[NSLOTS + s]; }
    double loss = LN2 * (acc_a - (10.0 / 65536.0) * acc_r);
    out[0] = (float)loss;
}

extern "C" void kernel_launch(void* const* d_in, const int* in_sizes, int n_in,
                              void* d_out, int out_size, void* d_ws, size_t ws_size,
                              hipStream_t stream) {
    const float* emb    = (const float*)d_in[0];
    const float* sparse = (const float*)d_in[1];
    const float* deg    = (const float*)d_in[2];
    const int*   heads  = (const int*)d_in[3];
    const int*   tails  = (const int*)d_in[4];
    float* out = (float*)d_out;
    double* ws = (double*)d_ws;

    hipLaunchKernelGGL(init_acc_kernel, dim3(1), dim3(128), 0, stream, ws);
    hipLaunchKernelGGL(fused_kernel, dim3(NB), dim3(256), 0, stream,
                       emb, deg, sparse, heads, tails, ws);
    hipLaunchKernelGGL(finalize_kernel, dim3(1), dim3(1), 0, stream, ws, out);
}